// Round 15
// baseline (673.337 us; speedup 1.0000x reference)
//
#include <hip/hip_runtime.h>

// GCN layer, E=1.6M, N=50000, F=48.
//   node_h = segment_mean(edge_feats, dst)
//   h2     = segment_sum(node_h[src], dst)
//   out[e] = 0.5*(h2[src]+h2[dst]) @ W^T + b
// Algebra: h2W = 0.5*(h2 @ W^T) + 0.5*b; out[e]=h2W[src]+h2W[dst].
// R2: fp atomics -> ~1 mem transaction per ~4 atomics; use CSR/ELL + gather.
// R3: in-graph hipMemsetAsync dispatches a slow fill -> own zero kernel.
// R4/R12: __builtin_nontemporal_* needs ext_vector types, NOT HIP float4/int4.
// R5/R6: coalesced scan; int2 payload (-102us). R7: f16 tables (-23us).
// R8/R9: cooperative single-dispatch FAILED (1300us). Full-op traffic 850MB.
// R10 diagnostic: data-plane (nh+h2lin+eo) ~106-196us.
// R11: one-pass padded ELL build (390us). R13: LDS-staging regressed; reverted.
// R14: confirmed 387us. Accounting does NOT close: {zero,fillpad,boundaries}
//   ~190-280us vs first-principles ~30us for fillpad. Can't declare roofline.
// R15 (THIS ROUND): pure diagnostic. Repeat {zero,fillpad} x3 (pair is
//   idempotent: same slot-set rewritten; final pair defines consumed state).
//   dur - 387 = 2*(t_zero + t_fill + 2*boundary). Pre-committed read:
//   high (~+350) -> fix fillpad mechanism; low (~+70) -> attack gather kernels.

constexpr int NN   = 50000;
constexpr int F    = 48;
constexpr int F4   = F / 4;
constexpr int ELLW = 64;              // padded row width (mean deg 32)

typedef float    f32x4 __attribute__((ext_vector_type(4)));
typedef _Float16 f16x4 __attribute__((ext_vector_type(4)));

// ---- zero cursor ---------------------------------------------------------
__global__ void k_zero(int* __restrict__ p, int n) {
    int i = blockIdx.x * blockDim.x + threadIdx.x;
    if (i < n) p[i] = 0;
}

// ---- one-pass ELL build: ell[dst*64 + slot] = {edge, src} ----------------
__global__ void k_fillpad(const int4* __restrict__ src4, const int4* __restrict__ dst4,
                          int* __restrict__ cursor, int2* __restrict__ ell, int E4) {
    int i = blockIdx.x * blockDim.x + threadIdx.x;
    if (i >= E4) return;
    int4 s = src4[i];
    int4 d = dst4[i];
    int e = i * 4;
    int p0 = atomicAdd(&cursor[d.x], 1);
    int p1 = atomicAdd(&cursor[d.y], 1);
    int p2 = atomicAdd(&cursor[d.z], 1);
    int p3 = atomicAdd(&cursor[d.w], 1);
    if (p0 < ELLW) ell[d.x * ELLW + p0] = make_int2(e + 0, s.x);
    if (p1 < ELLW) ell[d.y * ELLW + p1] = make_int2(e + 1, s.y);
    if (p2 < ELLW) ell[d.z * ELLW + p2] = make_int2(e + 2, s.z);
    if (p3 < ELLW) ell[d.w * ELLW + p3] = make_int2(e + 3, s.w);
}

// ---- node_h = segment_mean(ef) -> f16; thread per (node, quad) -----------
__global__ __launch_bounds__(256) void k_node_h(
    const f32x4* __restrict__ ef4, const int2* __restrict__ ell,
    const int* __restrict__ degv, f16x4* __restrict__ nh16, int total)
{
    int idx = blockIdx.x * blockDim.x + threadIdx.x;
    if (idx >= total) return;
    int n = idx / F4;
    int q = idx - n * F4;
    int deg = degv[n];
    int lo = n * ELLW, hi = lo + min(deg, ELLW);
    f32x4 acc = (f32x4)(0.f);
    int j = lo;
    for (; j + 8 <= hi; j += 8) {           // 8 x 16B loads in flight
        int e0 = ell[j].x,     e1 = ell[j + 1].x;
        int e2 = ell[j + 2].x, e3 = ell[j + 3].x;
        int e4 = ell[j + 4].x, e5 = ell[j + 5].x;
        int e6 = ell[j + 6].x, e7 = ell[j + 7].x;
        f32x4 a0 = __builtin_nontemporal_load(&ef4[e0 * F4 + q]);
        f32x4 a1 = __builtin_nontemporal_load(&ef4[e1 * F4 + q]);
        f32x4 a2 = __builtin_nontemporal_load(&ef4[e2 * F4 + q]);
        f32x4 a3 = __builtin_nontemporal_load(&ef4[e3 * F4 + q]);
        f32x4 a4 = __builtin_nontemporal_load(&ef4[e4 * F4 + q]);
        f32x4 a5 = __builtin_nontemporal_load(&ef4[e5 * F4 + q]);
        f32x4 a6 = __builtin_nontemporal_load(&ef4[e6 * F4 + q]);
        f32x4 a7 = __builtin_nontemporal_load(&ef4[e7 * F4 + q]);
        acc += a0 + a1 + a2 + a3 + a4 + a5 + a6 + a7;
    }
    for (; j < hi; j++)
        acc += __builtin_nontemporal_load(&ef4[ell[j].x * F4 + q]);
    float inv = 1.0f / fmaxf((float)deg, 1.0f);
    acc *= inv;
    nh16[idx] = __builtin_convertvector(acc, f16x4);
}

// ---- fused h2-aggregate + linear: block = 192 = 16 nodes x 12 lanes ------
__global__ __launch_bounds__(192) void k_h2lin(
    const f16x4* __restrict__ nh16, const int2* __restrict__ ell,
    const int* __restrict__ degv, const float* __restrict__ W,
    const float* __restrict__ b, f16x4* __restrict__ h2W16)
{
    __shared__ float h2s[16][F + 1];        // +1 pad
    int t = threadIdx.x;
    int nl = t / F4, q = t - nl * F4;
    int node = blockIdx.x * 16 + nl;        // NN = 3125*16 exactly

    int deg = degv[node];
    int lo = node * ELLW, hi = lo + min(deg, ELLW);
    f32x4 acc = (f32x4)(0.f);
    int j = lo;
    for (; j + 4 <= hi; j += 4) {
        int s0 = ell[j].y,     s1 = ell[j + 1].y;
        int s2 = ell[j + 2].y, s3 = ell[j + 3].y;
        f32x4 a0 = __builtin_convertvector(nh16[s0 * F4 + q], f32x4);
        f32x4 a1 = __builtin_convertvector(nh16[s1 * F4 + q], f32x4);
        f32x4 a2 = __builtin_convertvector(nh16[s2 * F4 + q], f32x4);
        f32x4 a3 = __builtin_convertvector(nh16[s3 * F4 + q], f32x4);
        acc += a0 + a1 + a2 + a3;
    }
    for (; j < hi; j++)
        acc += __builtin_convertvector(nh16[ell[j].y * F4 + q], f32x4);

    h2s[nl][q * 4 + 0] = acc.x;
    h2s[nl][q * 4 + 1] = acc.y;
    h2s[nl][q * 4 + 2] = acc.z;
    h2s[nl][q * 4 + 3] = acc.w;
    __syncthreads();

    const float* row = h2s[nl];
    const float* W0 = W + (q * 4 + 0) * F;
    const float* W1 = W + (q * 4 + 1) * F;
    const float* W2 = W + (q * 4 + 2) * F;
    const float* W3 = W + (q * 4 + 3) * F;
    float o0 = 0.f, o1 = 0.f, o2 = 0.f, o3 = 0.f;
#pragma unroll
    for (int i = 0; i < F; i++) {
        float hv = row[i];
        o0 += hv * W0[i];
        o1 += hv * W1[i];
        o2 += hv * W2[i];
        o3 += hv * W3[i];
    }
    const f32x4* b4 = (const f32x4*)b;
    f32x4 r; r.x = o0; r.y = o1; r.z = o2; r.w = o3;
    r = 0.5f * r + 0.5f * b4[q];
    h2W16[node * F4 + q] = __builtin_convertvector(r, f16x4);
}

// ---- edge out: grid-stride thread per (edge, quad); nt f32 store ---------
__global__ __launch_bounds__(256) void k_edge_out(
    const int* __restrict__ src, const int* __restrict__ dst,
    const f16x4* __restrict__ h2W16, f32x4* __restrict__ out4, int total)
{
    int stride = gridDim.x * blockDim.x;
    for (int idx = blockIdx.x * blockDim.x + threadIdx.x; idx < total; idx += stride) {
        int e = idx / F4;
        int q = idx - e * F4;
        f32x4 x = __builtin_convertvector(h2W16[src[e] * F4 + q], f32x4);
        f32x4 y = __builtin_convertvector(h2W16[dst[e] * F4 + q], f32x4);
        f32x4 r = x + y;
        __builtin_nontemporal_store(r, &out4[idx]);
    }
}

extern "C" void kernel_launch(void* const* d_in, const int* in_sizes, int n_in,
                              void* d_out, int out_size, void* d_ws, size_t ws_size,
                              hipStream_t stream) {
    const float* ef  = (const float*)d_in[0];
    const int*   src = (const int*)d_in[1];
    const int*   dst = (const int*)d_in[2];
    const float* W   = (const float*)d_in[3];
    const float* b   = (const float*)d_in[4];
    float* out = (float*)d_out;
    const int E = in_sizes[1];

    // ws layout, 16B-aligned sections:
    _Float16* nh16  = (_Float16*)d_ws;              // NN*F halves (4.8MB)
    _Float16* h2W16 = nh16 + NN * F;                // NN*F halves (4.8MB)
    int2* ell       = (int2*)(h2W16 + NN * F);      // NN*64 int2 (25.6MB)
    int* cursor     = (int*)(ell + (size_t)NN * ELLW);  // NN ints (=deg after fill)

    const int totN4 = NN * F4;                      // 600K
    const int totE4 = E * F4;                       // 19.2M
    const int E4 = E / 4;                           // 400K (E divisible by 4)

    // DIAGNOSTIC: run the {zero,fill} pair 3x. Pair is idempotent (each fill
    // rewrites exactly the slot-set {(d, 0..deg(d)-1)}; last pair wins).
    // dur_us - 387 = 2 * (t_zero + t_fill + 2*boundary).
    for (int rep = 0; rep < 3; rep++) {
        k_zero<<<(NN + 255) / 256, 256, 0, stream>>>(cursor, NN);
        k_fillpad<<<(E4 + 255) / 256, 256, 0, stream>>>(
            (const int4*)src, (const int4*)dst, cursor, ell, E4);
    }
    k_node_h<<<(totN4 + 255) / 256, 256, 0, stream>>>(
        (const f32x4*)ef, ell, cursor, (f16x4*)nh16, totN4);
    k_h2lin<<<NN / 16, 192, 0, stream>>>(
        (const f16x4*)nh16, ell, cursor, W, b, (f16x4*)h2W16);
    k_edge_out<<<4096, 256, 0, stream>>>(
        src, dst, (const f16x4*)h2W16, (f32x4*)out, totE4);
}

// Round 16
// 379.932 us; speedup vs baseline: 1.7723x; 1.7723x over previous
//
#include <hip/hip_runtime.h>

// GCN layer, E=1.6M, N=50000, F=48.
//   node_h = segment_mean(edge_feats, dst)
//   h2     = segment_sum(node_h[src], dst)
//   out[e] = 0.5*(h2[src]+h2[dst]) @ W^T + b
// Algebra: h2W = 0.5*(h2 @ W^T) + 0.5*b; out[e]=h2W[src]+h2W[dst].
// R2: fp atomics -> ~1 mem transaction per ~4 atomics; use CSR/ELL + gather.
// R3: in-graph hipMemsetAsync dispatches a slow fill -> own zero kernel.
// R4/R12: __builtin_nontemporal_* needs ext_vector types, NOT HIP float4/int4.
// R5/R6: coalesced scan; int2 payload (-102us). R7: f16 tables (-23us).
// R8/R9: cooperative single-dispatch FAILED (1300us). Full-op traffic 850MB.
// R11: one-pass padded ELL build (387us best). R13: LDS staging regressed.
// R15 diagnostic: {zero,fillpad}+2 boundaries = 143us timing-mode; fill alone
//   ~100-115us vs ~30us first-principles -> ~70-80us in the 1.6M device-scope
//   atomics. Per-counter contention math rules out counter serialization;
//   cursor packs 16 counters/64B line (3125 lines, 512 RMW/line) -> test
//   LINE-serialization hypothesis.
// R16: pad cursor to 1 counter per 64B line (cursor[d*16]). If fill drops
//   ~50-80us -> mechanism confirmed. If unchanged -> atomic throughput is the
//   HW limit and R14's 387us is the roofline (arithmetic closes).

constexpr int NN   = 50000;
constexpr int F    = 48;
constexpr int F4   = F / 4;
constexpr int ELLW = 64;              // padded row width (mean deg 32)
constexpr int CPAD = 16;              // cursor padding: 1 counter / 64B line

typedef float    f32x4 __attribute__((ext_vector_type(4)));
typedef _Float16 f16x4 __attribute__((ext_vector_type(4)));

// ---- zero cursor ---------------------------------------------------------
__global__ void k_zero(int* __restrict__ p, int n) {
    int i = blockIdx.x * blockDim.x + threadIdx.x;
    if (i < n) p[i] = 0;
}

// ---- one-pass ELL build: ell[dst*64 + slot] = {edge, src} ----------------
__global__ void k_fillpad(const int4* __restrict__ src4, const int4* __restrict__ dst4,
                          int* __restrict__ cursor, int2* __restrict__ ell, int E4) {
    int i = blockIdx.x * blockDim.x + threadIdx.x;
    if (i >= E4) return;
    int4 s = src4[i];
    int4 d = dst4[i];
    int e = i * 4;
    int p0 = atomicAdd(&cursor[d.x * CPAD], 1);
    int p1 = atomicAdd(&cursor[d.y * CPAD], 1);
    int p2 = atomicAdd(&cursor[d.z * CPAD], 1);
    int p3 = atomicAdd(&cursor[d.w * CPAD], 1);
    if (p0 < ELLW) ell[d.x * ELLW + p0] = make_int2(e + 0, s.x);
    if (p1 < ELLW) ell[d.y * ELLW + p1] = make_int2(e + 1, s.y);
    if (p2 < ELLW) ell[d.z * ELLW + p2] = make_int2(e + 2, s.z);
    if (p3 < ELLW) ell[d.w * ELLW + p3] = make_int2(e + 3, s.w);
}

// ---- node_h = segment_mean(ef) -> f16; thread per (node, quad) -----------
__global__ __launch_bounds__(256) void k_node_h(
    const f32x4* __restrict__ ef4, const int2* __restrict__ ell,
    const int* __restrict__ degv, f16x4* __restrict__ nh16, int total)
{
    int idx = blockIdx.x * blockDim.x + threadIdx.x;
    if (idx >= total) return;
    int n = idx / F4;
    int q = idx - n * F4;
    int deg = degv[n * CPAD];
    int lo = n * ELLW, hi = lo + min(deg, ELLW);
    f32x4 acc = (f32x4)(0.f);
    int j = lo;
    for (; j + 8 <= hi; j += 8) {           // 8 x 16B loads in flight
        int e0 = ell[j].x,     e1 = ell[j + 1].x;
        int e2 = ell[j + 2].x, e3 = ell[j + 3].x;
        int e4 = ell[j + 4].x, e5 = ell[j + 5].x;
        int e6 = ell[j + 6].x, e7 = ell[j + 7].x;
        f32x4 a0 = __builtin_nontemporal_load(&ef4[e0 * F4 + q]);
        f32x4 a1 = __builtin_nontemporal_load(&ef4[e1 * F4 + q]);
        f32x4 a2 = __builtin_nontemporal_load(&ef4[e2 * F4 + q]);
        f32x4 a3 = __builtin_nontemporal_load(&ef4[e3 * F4 + q]);
        f32x4 a4 = __builtin_nontemporal_load(&ef4[e4 * F4 + q]);
        f32x4 a5 = __builtin_nontemporal_load(&ef4[e5 * F4 + q]);
        f32x4 a6 = __builtin_nontemporal_load(&ef4[e6 * F4 + q]);
        f32x4 a7 = __builtin_nontemporal_load(&ef4[e7 * F4 + q]);
        acc += a0 + a1 + a2 + a3 + a4 + a5 + a6 + a7;
    }
    for (; j < hi; j++)
        acc += __builtin_nontemporal_load(&ef4[ell[j].x * F4 + q]);
    float inv = 1.0f / fmaxf((float)deg, 1.0f);
    acc *= inv;
    nh16[idx] = __builtin_convertvector(acc, f16x4);
}

// ---- fused h2-aggregate + linear: block = 192 = 16 nodes x 12 lanes ------
__global__ __launch_bounds__(192) void k_h2lin(
    const f16x4* __restrict__ nh16, const int2* __restrict__ ell,
    const int* __restrict__ degv, const float* __restrict__ W,
    const float* __restrict__ b, f16x4* __restrict__ h2W16)
{
    __shared__ float h2s[16][F + 1];        // +1 pad
    int t = threadIdx.x;
    int nl = t / F4, q = t - nl * F4;
    int node = blockIdx.x * 16 + nl;        // NN = 3125*16 exactly

    int deg = degv[node * CPAD];
    int lo = node * ELLW, hi = lo + min(deg, ELLW);
    f32x4 acc = (f32x4)(0.f);
    int j = lo;
    for (; j + 4 <= hi; j += 4) {
        int s0 = ell[j].y,     s1 = ell[j + 1].y;
        int s2 = ell[j + 2].y, s3 = ell[j + 3].y;
        f32x4 a0 = __builtin_convertvector(nh16[s0 * F4 + q], f32x4);
        f32x4 a1 = __builtin_convertvector(nh16[s1 * F4 + q], f32x4);
        f32x4 a2 = __builtin_convertvector(nh16[s2 * F4 + q], f32x4);
        f32x4 a3 = __builtin_convertvector(nh16[s3 * F4 + q], f32x4);
        acc += a0 + a1 + a2 + a3;
    }
    for (; j < hi; j++)
        acc += __builtin_convertvector(nh16[ell[j].y * F4 + q], f32x4);

    h2s[nl][q * 4 + 0] = acc.x;
    h2s[nl][q * 4 + 1] = acc.y;
    h2s[nl][q * 4 + 2] = acc.z;
    h2s[nl][q * 4 + 3] = acc.w;
    __syncthreads();

    const float* row = h2s[nl];
    const float* W0 = W + (q * 4 + 0) * F;
    const float* W1 = W + (q * 4 + 1) * F;
    const float* W2 = W + (q * 4 + 2) * F;
    const float* W3 = W + (q * 4 + 3) * F;
    float o0 = 0.f, o1 = 0.f, o2 = 0.f, o3 = 0.f;
#pragma unroll
    for (int i = 0; i < F; i++) {
        float hv = row[i];
        o0 += hv * W0[i];
        o1 += hv * W1[i];
        o2 += hv * W2[i];
        o3 += hv * W3[i];
    }
    const f32x4* b4 = (const f32x4*)b;
    f32x4 r; r.x = o0; r.y = o1; r.z = o2; r.w = o3;
    r = 0.5f * r + 0.5f * b4[q];
    h2W16[node * F4 + q] = __builtin_convertvector(r, f16x4);
}

// ---- edge out: grid-stride thread per (edge, quad); nt f32 store ---------
__global__ __launch_bounds__(256) void k_edge_out(
    const int* __restrict__ src, const int* __restrict__ dst,
    const f16x4* __restrict__ h2W16, f32x4* __restrict__ out4, int total)
{
    int stride = gridDim.x * blockDim.x;
    for (int idx = blockIdx.x * blockDim.x + threadIdx.x; idx < total; idx += stride) {
        int e = idx / F4;
        int q = idx - e * F4;
        f32x4 x = __builtin_convertvector(h2W16[src[e] * F4 + q], f32x4);
        f32x4 y = __builtin_convertvector(h2W16[dst[e] * F4 + q], f32x4);
        f32x4 r = x + y;
        __builtin_nontemporal_store(r, &out4[idx]);
    }
}

extern "C" void kernel_launch(void* const* d_in, const int* in_sizes, int n_in,
                              void* d_out, int out_size, void* d_ws, size_t ws_size,
                              hipStream_t stream) {
    const float* ef  = (const float*)d_in[0];
    const int*   src = (const int*)d_in[1];
    const int*   dst = (const int*)d_in[2];
    const float* W   = (const float*)d_in[3];
    const float* b   = (const float*)d_in[4];
    float* out = (float*)d_out;
    const int E = in_sizes[1];

    // ws layout, 16B-aligned sections:
    _Float16* nh16  = (_Float16*)d_ws;              // NN*F halves (4.8MB)
    _Float16* h2W16 = nh16 + NN * F;                // NN*F halves (4.8MB)
    int2* ell       = (int2*)(h2W16 + NN * F);      // NN*64 int2 (25.6MB)
    int* cursor     = (int*)(ell + (size_t)NN * ELLW);  // NN*16 ints padded (3.2MB)

    const int totN4 = NN * F4;                      // 600K
    const int totE4 = E * F4;                       // 19.2M
    const int E4 = E / 4;                           // 400K (E divisible by 4)

    k_zero<<<(NN * CPAD + 255) / 256, 256, 0, stream>>>(cursor, NN * CPAD);
    k_fillpad<<<(E4 + 255) / 256, 256, 0, stream>>>(
        (const int4*)src, (const int4*)dst, cursor, ell, E4);
    k_node_h<<<(totN4 + 255) / 256, 256, 0, stream>>>(
        (const f32x4*)ef, ell, cursor, (f16x4*)nh16, totN4);
    k_h2lin<<<NN / 16, 192, 0, stream>>>(
        (const f16x4*)nh16, ell, cursor, W, b, (f16x4*)h2W16);
    k_edge_out<<<4096, 256, 0, stream>>>(
        src, dst, (const f16x4*)h2W16, (f32x4*)out, totE4);
}